// Round 8
// baseline (257.889 us; speedup 1.0000x reference)
//
#include <hip/hip_runtime.h>
#include <hip/hip_bf16.h>
#include <stdint.h>

#define NN 8192
#define FIN 512
#define FOUT 256
#define ALPHAV 0.2f
#define MASKF 9e-15f
#define L2E 1.44269504088896340736f

typedef __attribute__((ext_vector_type(8))) short bf16x8;
typedef __attribute__((ext_vector_type(4))) float f32x4;
typedef __attribute__((ext_vector_type(16))) float f32x16;
typedef unsigned long long u64;

static __device__ __forceinline__ float ex2(float x){
#if __has_builtin(__builtin_amdgcn_exp2f)
  return __builtin_amdgcn_exp2f(x);
#else
  return exp2f(x);
#endif
}
static __device__ __forceinline__ unsigned short f2bf(float f){
  __bf16 b = (__bf16)f;
  return __builtin_bit_cast(unsigned short, b);
}

// ---------------- K1: hTt(bf16, granule-tiled) = (x@W)^T, fused f1/f2 -----
// hTt layout: [ktile=j/32][g=(j&31)/8][col][j&7] — 16 KB per ktile, byte-
// sequential for spmm staging AND conflict-free for 32x32 B-frag ds_reads.
__global__ __launch_bounds__(256, 2) void k_gemm_h(
    const float* __restrict__ x, const float* __restrict__ Wm,
    const float* __restrict__ aG, unsigned short* __restrict__ hTt,
    float* __restrict__ f1, float* __restrict__ f2)
{
  __shared__ __align__(16) float Bs[4096];   // 16x256 W tile, staging order
  __shared__ __align__(16) float xs[8192];   // 16 rows x 512 k (32 KB)
  const int t  = threadIdx.x;
  const int rg = t >> 6;          // wave -> 4 rows (j)
  const int cg = t & 63;          // lane -> 4 cols (n)
  const int i0 = blockIdx.x * 16;
  const int wk = t >> 4;
  const int wc = (t & 15) * 4;

  {
    const int xr = t >> 7;
    const int xc = (t & 127) * 4;
#pragma unroll
    for (int c = 0; c < 8; ++c) {
      const float* gp = x + (size_t)(i0 + c * 2 + xr) * FIN + xc;
      char* lp = ((char*)xs) + c * 4096 + t * 16;
      __builtin_amdgcn_global_load_lds(
          (const __attribute__((address_space(1))) unsigned int*)gp,
          (__attribute__((address_space(3))) unsigned int*)lp, 16, 0, 0);
    }
  }

  float acc[4][4];
#pragma unroll
  for (int r = 0; r < 4; ++r)
#pragma unroll
    for (int c = 0; c < 4; ++c) acc[r][c] = 0.f;

  float4 wreg[4];
#pragma unroll
  for (int q = 0; q < 4; ++q)
    wreg[q] = *(const float4*)(Wm + (size_t)wk * FOUT + q * 64 + wc);

  for (int k0 = 0; k0 < FIN; k0 += 16) {
    __syncthreads();
#pragma unroll
    for (int q = 0; q < 4; ++q)
      *(float4*)(&Bs[q * 1024 + t * 4]) = wreg[q];
    __syncthreads();
    if (k0 + 16 < FIN) {
#pragma unroll
      for (int q = 0; q < 4; ++q)
        wreg[q] = *(const float4*)(Wm + (size_t)(k0 + 16 + wk) * FOUT + q * 64 + wc);
    }
#pragma unroll
    for (int q = 0; q < 4; ++q) {
      float4 xa[4];
#pragma unroll
      for (int r = 0; r < 4; ++r)
        xa[r] = *(const float4*)(&xs[(rg * 4 + r) * 512 + k0 + q * 4]);
#pragma unroll
      for (int k2 = 0; k2 < 4; ++k2) {
        const int kk = q * 4 + k2;
        float4 bv = *(const float4*)(&Bs[(cg >> 4) * 1024 + kk * 64 + (cg & 15) * 4]);
        float bb4[4] = {bv.x, bv.y, bv.z, bv.w};
#pragma unroll
        for (int r = 0; r < 4; ++r) {
          float ar = (k2 == 0) ? xa[r].x : (k2 == 1) ? xa[r].y : (k2 == 2) ? xa[r].z : xa[r].w;
#pragma unroll
          for (int c = 0; c < 4; ++c) acc[r][c] = fmaf(ar, bb4[c], acc[r][c]);
        }
      }
    }
  }
  // granule-tiled store: (col, j) -> hTt[kt*8192 + (jin>>3)*2048 + col*8 + (jin&7)]
  const int j0  = i0 + rg * 4;
  const int kt  = j0 >> 5;
  const int jin = j0 & 31;
  const size_t sbase = (size_t)kt * 8192 + (size_t)(jin >> 3) * 2048 + (jin & 7);
#pragma unroll
  for (int c = 0; c < 4; ++c) {
    int col = cg * 4 + c;
    ushort4 u;
    u.x = f2bf(acc[0][c]); u.y = f2bf(acc[1][c]);
    u.z = f2bf(acc[2][c]); u.w = f2bf(acc[3][c]);
    *(ushort4*)(hTt + sbase + col * 8) = u;
  }
  float4 a1 = *(const float4*)(aG + cg * 4);
  float4 a2 = *(const float4*)(aG + FOUT + cg * 4);
#pragma unroll
  for (int r = 0; r < 4; ++r) {
    float s1 = acc[r][0]*a1.x + acc[r][1]*a1.y + acc[r][2]*a1.z + acc[r][3]*a1.w;
    float s2 = acc[r][0]*a2.x + acc[r][1]*a2.y + acc[r][2]*a2.z + acc[r][3]*a2.w;
#pragma unroll
    for (int off = 32; off > 0; off >>= 1) {
      s1 += __shfl_xor(s1, off);
      s2 += __shfl_xor(s2, off);
    }
    if (cg == 0) { f1[i0 + rg * 4 + r] = s1; f2[i0 + rg * 4 + r] = s2; }
  }
}

// ---------------- K2: row-max UPPER BOUND m̂_i = lrelu(f1_i + max f2) ------
__global__ __launch_bounds__(1024) void k_bound(
    const float* __restrict__ f1, const float* __restrict__ f2,
    float* __restrict__ mhat)
{
  __shared__ float red[16];
  const int t = threadIdx.x;
  float m = -3.0e38f;
#pragma unroll
  for (int k = 0; k < 8; ++k) m = fmaxf(m, f2[t + k * 1024]);
#pragma unroll
  for (int off = 32; off > 0; off >>= 1) m = fmaxf(m, __shfl_xor(m, off));
  if ((t & 63) == 0) red[t >> 6] = m;
  __syncthreads();
  float fm = red[0];
#pragma unroll
  for (int w = 1; w < 16; ++w) fm = fmaxf(fm, red[w]);
#pragma unroll
  for (int k = 0; k < 8; ++k) {
    int i = t + k * 1024;
    float s = f1[i] + fm;
    mhat[i] = fmaxf(fmaxf(s, ALPHAV * s), MASKF);
  }
}

// ---------------- K3: FUSED adj + P-regen + (P@h) via 32x32x16 MFMA -------
// 8 waves = 2(wr: 32 rows) x 4(wc: 64 cols); BM=64, BN=256, kslice=1024.
// grid (128, 8) = 1024 blocks. acc = 2x16 f32/wave. 3 LDS bufs, depth-2
// prefetch (adj->regs, hTt->LDS sequential), counted vmcnt(6), ONE barrier
// per tile. B ds_reads 512B-contiguous (conflict-free, no swizzle).
__global__ __launch_bounds__(512, 4) void k_spmm(
    const unsigned short* __restrict__ hTt,
    const int* __restrict__ adj,
    const float* __restrict__ f1, const float* __restrict__ f2,
    const float* __restrict__ mhat,
    float* __restrict__ part, float* __restrict__ rowsumP)
{
  __shared__ __align__(16) unsigned short hbuf[3 * 8192]; // 3 x 16 KB
  __shared__ __align__(16) float f2s[1024];               // pre-scaled by L2E
  const int t  = threadIdx.x;
  const int wv = t >> 6;
  const int l  = t & 63;
  const int wr = wv >> 2;          // 0..1: row group (32 rows)
  const int wc = wv & 3;           // 0..3: col group (64 cols)
  const int bx = blockIdx.x;
  const int ks = blockIdx.y;
  const int r0 = bx * 64;
  const int s8 = (l >> 5) * 8;     // k-subslot of this half-wave

  // consts first (their waits land before the counted stream starts)
  const int rA = r0 + wr * 32 + (l & 31);
  const float nmA   = -mhat[rA] * L2E;
  const float base0 = fmaf(f1[rA], L2E, nmA);
  const float c20   = nmA * (1.f - ALPHAV);
  const float mc0   = fmaf(MASKF, L2E, nmA);
  const int* aP = adj + (size_t)rA * NN + ks * 1024 + s8;

  // f2 slice -> LDS (pre-scaled); value-use forces its vmem drain here
  if (t < 256) {
    float4 v = *(const float4*)(f2 + ks * 1024 + t * 4);
    v.x *= L2E; v.y *= L2E; v.z *= L2E; v.w *= L2E;
    *(float4*)(&f2s[t * 4]) = v;
  }
  asm volatile("" ::: "memory");   // fence: counted stream starts below

  f32x16 acc0, acc1;
#pragma unroll
  for (int e = 0; e < 16; ++e) { acc0[e] = 0.f; acc1[e] = 0.f; }
  float sumP = 0.f;

  const size_t tilesz = 8192;      // ushorts per 32-j tile
  const unsigned short* gt0 = hTt + (size_t)ks * 32 * tilesz;
  const int lane_b = (l >> 5) * 4096 + (l & 31) * 16 + wc * 1024;

#define SB0 __builtin_amdgcn_sched_barrier(0)
#define STAGE(BUFI, JT)                                                       \
  do {                                                                        \
    const unsigned short* gp_ = gt0 + (size_t)(JT) * tilesz + t * 8;          \
    char* lp_ = ((char*)hbuf) + (BUFI) * 16384 + t * 16;                      \
    __builtin_amdgcn_global_load_lds(                                         \
        (const __attribute__((address_space(1))) unsigned int*)gp_,           \
        (__attribute__((address_space(3))) unsigned int*)lp_, 16, 0, 0);      \
    __builtin_amdgcn_global_load_lds(                                         \
        (const __attribute__((address_space(1))) unsigned int*)(gp_ + 4096),  \
        (__attribute__((address_space(3))) unsigned int*)(lp_ + 8192), 16, 0, 0); \
  } while (0)

#define REGEN8(AFR, AV0, AV1, FB)                                             \
  do {                                                                        \
    float4 fx_ = *(const float4*)(&f2s[FB]);                                  \
    float4 fy_ = *(const float4*)(&f2s[(FB) + 4]);                            \
    float fv_[8] = {fx_.x, fx_.y, fx_.z, fx_.w, fy_.x, fy_.y, fy_.z, fy_.w};  \
    int av_[8] = {AV0.x, AV0.y, AV0.z, AV0.w, AV1.x, AV1.y, AV1.z, AV1.w};    \
    _Pragma("unroll")                                                         \
    for (int b = 0; b < 8; ++b) {                                             \
      float u_ = base0 + fv_[b];                                              \
      float w_ = fmaxf(u_, fmaf(ALPHAV, u_, c20));                            \
      w_ = (av_[b] > 0) ? w_ : mc0;                                           \
      float p_ = ex2(w_);                                                     \
      sumP += p_;                                                             \
      AFR[b] = (short)f2bf(p_);                                               \
    }                                                                         \
  } while (0)

#define TS(JT, CUR, PRE, A0, A1, A2, A3, DOISSUE, VMC)                        \
  do {                                                                        \
    asm volatile("s_waitcnt vmcnt(" #VMC ")" ::: "memory");                   \
    __builtin_amdgcn_s_barrier();                                             \
    SB0;                                                                      \
    bf16x8 afr0_, afr1_;                                                      \
    REGEN8(afr0_, A0, A1, (JT) * 32 + s8);                                    \
    REGEN8(afr1_, A2, A3, (JT) * 32 + 16 + s8);                               \
    if (DOISSUE) {                                                            \
      A0 = *(const int4*)(aP + (JT + 2) * 32);                                \
      A1 = *(const int4*)(aP + (JT + 2) * 32 + 4);                            \
      A2 = *(const int4*)(aP + (JT + 2) * 32 + 16);                           \
      A3 = *(const int4*)(aP + (JT + 2) * 32 + 20);                           \
      STAGE(PRE, JT + 2);                                                     \
    }                                                                         \
    const char* lb_ = ((const char*)hbuf) + (CUR) * 16384;                    \
    __builtin_amdgcn_s_setprio(1);                                            \
    bf16x8 bb0_ = *(const bf16x8*)(lb_ + lane_b);                             \
    acc0 = __builtin_amdgcn_mfma_f32_32x32x16_bf16(afr0_, bb0_, acc0, 0, 0, 0); \
    bf16x8 bb1_ = *(const bf16x8*)(lb_ + lane_b + 512);                       \
    acc1 = __builtin_amdgcn_mfma_f32_32x32x16_bf16(afr0_, bb1_, acc1, 0, 0, 0); \
    bf16x8 bb2_ = *(const bf16x8*)(lb_ + lane_b + 8192);                      \
    acc0 = __builtin_amdgcn_mfma_f32_32x32x16_bf16(afr1_, bb2_, acc0, 0, 0, 0); \
    bf16x8 bb3_ = *(const bf16x8*)(lb_ + lane_b + 8192 + 512);                \
    acc1 = __builtin_amdgcn_mfma_f32_32x32x16_bf16(afr1_, bb3_, acc1, 0, 0, 0); \
    __builtin_amdgcn_s_setprio(0);                                            \
  } while (0)

  // prologue: counted stream = [adj(0) x4, stage(0) x2, adj(1) x4, stage(1) x2]
  int4 xa0 = *(const int4*)(aP + 0),  xa1 = *(const int4*)(aP + 4);
  int4 xa2 = *(const int4*)(aP + 16), xa3 = *(const int4*)(aP + 20);
  STAGE(0, 0);
  asm volatile("" ::: "memory");
  int4 ya0 = *(const int4*)(aP + 32),      ya1 = *(const int4*)(aP + 32 + 4);
  int4 ya2 = *(const int4*)(aP + 32 + 16), ya3 = *(const int4*)(aP + 32 + 20);
  STAGE(1, 1);
  asm volatile("s_waitcnt lgkmcnt(0)" ::: "memory");  // f2s ds_writes done
  __builtin_amdgcn_s_barrier();
  SB0;

#pragma unroll 1
  for (int p = 0; p < 5; ++p) {
    const int j6 = p * 6;
    TS(j6 + 0, 0, 2, xa0, xa1, xa2, xa3, 1, 6);
    TS(j6 + 1, 1, 0, ya0, ya1, ya2, ya3, 1, 6);
    TS(j6 + 2, 2, 1, xa0, xa1, xa2, xa3, 1, 6);
    TS(j6 + 3, 0, 2, ya0, ya1, ya2, ya3, 1, 6);
    TS(j6 + 4, 1, 0, xa0, xa1, xa2, xa3, 1, 6);
    TS(j6 + 5, 2, 1, ya0, ya1, ya2, ya3, 1, 6);
  }
  TS(30, 0, 2, xa0, xa1, xa2, xa3, 0, 6);
  TS(31, 1, 0, ya0, ya1, ya2, ya3, 0, 0);

#undef SB0
#undef STAGE
#undef REGEN8
#undef TS

  // row sums: lanes l and l^32 hold the two k-halves of row (l&31)
  sumP += __shfl_xor(sumP, 32);
  if (wc == 0 && l < 32)
    rowsumP[(size_t)ks * NN + r0 + wr * 32 + l] = sumP;

  // C-write: col = wc*64 + c*32 + (l&31); row = (reg&3)+8*(reg>>2)+4*(l>>5)
  float* dst = part + (size_t)ks * NN * FOUT;
  const int colb = wc * 64 + (l & 31);
  const int rowb = r0 + wr * 32 + 4 * (l >> 5);
#pragma unroll
  for (int reg = 0; reg < 16; ++reg) {
    int row = rowb + (reg & 3) + 8 * (reg >> 2);
    dst[(size_t)row * FOUT + colb]      = acc0[reg];
    dst[(size_t)row * FOUT + colb + 32] = acc1[reg];
  }
}

// ---------------- K4: sum 8 K-partials + rowsums, normalize ---------------
__global__ __launch_bounds__(256) void k_fin(
    float* __restrict__ outp, const float* __restrict__ part,
    const float* __restrict__ rowsumP)
{
  const int idx4 = blockIdx.x * 256 + threadIdx.x;
  const size_t e = (size_t)idx4 * 4;
  const int i = (int)(e >> 8);
  float rs = 0.f;
#pragma unroll
  for (int p = 0; p < 8; ++p) rs += rowsumP[(size_t)p * NN + i];
  float4 o = {0.f, 0.f, 0.f, 0.f};
#pragma unroll
  for (int p = 0; p < 8; ++p) {
    float4 pv = *(const float4*)(part + (size_t)p * NN * FOUT + e);
    o.x += pv.x; o.y += pv.y; o.z += pv.z; o.w += pv.w;
  }
  float inv = 1.f / rs;
  o.x *= inv; o.y *= inv; o.z *= inv; o.w *= inv;
  *(float4*)(outp + e) = o;
}

extern "C" void kernel_launch(void* const* d_in, const int* in_sizes, int n_in,
                              void* d_out, int out_size, void* d_ws, size_t ws_size,
                              hipStream_t stream)
{
  const float* x  = (const float*)d_in[0];
  const int* adj  = (const int*)d_in[1];
  const float* Wm = (const float*)d_in[2];
  const float* aG = (const float*)d_in[3];
  float* outp = (float*)d_out;

  char* w = (char*)d_ws;
  unsigned short* hTt = (unsigned short*)(w + 0);            // 4 MB (tiled)
  float* f1           = (float*)(w + 4194304);               // 32 KB
  float* f2           = (float*)(w + 4227072);               // 32 KB
  float* mhat         = (float*)(w + 4259840);               // 32 KB
  float* rowsumP      = (float*)(w + 4292608);               // 256 KB
  float* part         = (float*)(w + 4554752);               // 64 MB (8 slices)

  hipLaunchKernelGGL(k_gemm_h, dim3(512),    dim3(256),  0, stream, x, Wm, aG, hTt, f1, f2);
  hipLaunchKernelGGL(k_bound,  dim3(1),      dim3(1024), 0, stream, f1, f2, mhat);
  hipLaunchKernelGGL(k_spmm,   dim3(128, 8), dim3(512),  0, stream, hTt, adj, f1, f2, mhat, part, rowsumP);
  hipLaunchKernelGGL(k_fin,    dim3(2048),   dim3(256),  0, stream, outp, part, rowsumP);
}

// Round 9
// 209.251 us; speedup vs baseline: 1.2324x; 1.2324x over previous
//
#include <hip/hip_runtime.h>
#include <hip/hip_bf16.h>
#include <stdint.h>

#define NN 8192
#define FIN 512
#define FOUT 256
#define ALPHAV 0.2f
#define MASKF 9e-15f
#define L2E 1.44269504088896340736f

typedef __attribute__((ext_vector_type(8))) short bf16x8;
typedef __attribute__((ext_vector_type(16))) float f32x16;
typedef unsigned long long u64;

static __device__ __forceinline__ float ex2(float x){
#if __has_builtin(__builtin_amdgcn_exp2f)
  return __builtin_amdgcn_exp2f(x);
#else
  return exp2f(x);
#endif
}
static __device__ __forceinline__ unsigned short f2bf(float f){
  __bf16 b = (__bf16)f;
  return __builtin_bit_cast(unsigned short, b);
}

// ---------------- K1: hTt(bf16, granule-tiled) = (x@W)^T, fused f1/f2 -----
// hTt layout: [ktile=j/32][g=(j&31)/8][col][j&7] — 16 KB per ktile.
__global__ __launch_bounds__(256, 2) void k_gemm_h(
    const float* __restrict__ x, const float* __restrict__ Wm,
    const float* __restrict__ aG, unsigned short* __restrict__ hTt,
    float* __restrict__ f1, float* __restrict__ f2)
{
  __shared__ __align__(16) float Bs[4096];   // 16x256 W tile, staging order
  __shared__ __align__(16) float xs[8192];   // 16 rows x 512 k (32 KB)
  const int t  = threadIdx.x;
  const int rg = t >> 6;
  const int cg = t & 63;
  const int i0 = blockIdx.x * 16;
  const int wk = t >> 4;
  const int wc = (t & 15) * 4;

  {
    const int xr = t >> 7;
    const int xc = (t & 127) * 4;
#pragma unroll
    for (int c = 0; c < 8; ++c) {
      const float* gp = x + (size_t)(i0 + c * 2 + xr) * FIN + xc;
      char* lp = ((char*)xs) + c * 4096 + t * 16;
      __builtin_amdgcn_global_load_lds(
          (const __attribute__((address_space(1))) unsigned int*)gp,
          (__attribute__((address_space(3))) unsigned int*)lp, 16, 0, 0);
    }
  }

  float acc[4][4];
#pragma unroll
  for (int r = 0; r < 4; ++r)
#pragma unroll
    for (int c = 0; c < 4; ++c) acc[r][c] = 0.f;

  float4 wreg[4];
#pragma unroll
  for (int q = 0; q < 4; ++q)
    wreg[q] = *(const float4*)(Wm + (size_t)wk * FOUT + q * 64 + wc);

  for (int k0 = 0; k0 < FIN; k0 += 16) {
    __syncthreads();
#pragma unroll
    for (int q = 0; q < 4; ++q)
      *(float4*)(&Bs[q * 1024 + t * 4]) = wreg[q];
    __syncthreads();
    if (k0 + 16 < FIN) {
#pragma unroll
      for (int q = 0; q < 4; ++q)
        wreg[q] = *(const float4*)(Wm + (size_t)(k0 + 16 + wk) * FOUT + q * 64 + wc);
    }
#pragma unroll
    for (int q = 0; q < 4; ++q) {
      float4 xa[4];
#pragma unroll
      for (int r = 0; r < 4; ++r)
        xa[r] = *(const float4*)(&xs[(rg * 4 + r) * 512 + k0 + q * 4]);
#pragma unroll
      for (int k2 = 0; k2 < 4; ++k2) {
        const int kk = q * 4 + k2;
        float4 bv = *(const float4*)(&Bs[(cg >> 4) * 1024 + kk * 64 + (cg & 15) * 4]);
        float bb4[4] = {bv.x, bv.y, bv.z, bv.w};
#pragma unroll
        for (int r = 0; r < 4; ++r) {
          float ar = (k2 == 0) ? xa[r].x : (k2 == 1) ? xa[r].y : (k2 == 2) ? xa[r].z : xa[r].w;
#pragma unroll
          for (int c = 0; c < 4; ++c) acc[r][c] = fmaf(ar, bb4[c], acc[r][c]);
        }
      }
    }
  }
  const int j0  = i0 + rg * 4;
  const int kt  = j0 >> 5;
  const int jin = j0 & 31;
  const size_t sbase = (size_t)kt * 8192 + (size_t)(jin >> 3) * 2048 + (jin & 7);
#pragma unroll
  for (int c = 0; c < 4; ++c) {
    int col = cg * 4 + c;
    ushort4 u;
    u.x = f2bf(acc[0][c]); u.y = f2bf(acc[1][c]);
    u.z = f2bf(acc[2][c]); u.w = f2bf(acc[3][c]);
    *(ushort4*)(hTt + sbase + col * 8) = u;
  }
  float4 a1 = *(const float4*)(aG + cg * 4);
  float4 a2 = *(const float4*)(aG + FOUT + cg * 4);
#pragma unroll
  for (int r = 0; r < 4; ++r) {
    float s1 = acc[r][0]*a1.x + acc[r][1]*a1.y + acc[r][2]*a1.z + acc[r][3]*a1.w;
    float s2 = acc[r][0]*a2.x + acc[r][1]*a2.y + acc[r][2]*a2.z + acc[r][3]*a2.w;
#pragma unroll
    for (int off = 32; off > 0; off >>= 1) {
      s1 += __shfl_xor(s1, off);
      s2 += __shfl_xor(s2, off);
    }
    if (cg == 0) { f1[i0 + rg * 4 + r] = s1; f2[i0 + rg * 4 + r] = s2; }
  }
}

// ---------------- K2: row-max UPPER BOUND m̂_i = lrelu(f1_i + max f2) ------
__global__ __launch_bounds__(1024) void k_bound(
    const float* __restrict__ f1, const float* __restrict__ f2,
    float* __restrict__ mhat)
{
  __shared__ float red[16];
  const int t = threadIdx.x;
  float m = -3.0e38f;
#pragma unroll
  for (int k = 0; k < 8; ++k) m = fmaxf(m, f2[t + k * 1024]);
#pragma unroll
  for (int off = 32; off > 0; off >>= 1) m = fmaxf(m, __shfl_xor(m, off));
  if ((t & 63) == 0) red[t >> 6] = m;
  __syncthreads();
  float fm = red[0];
#pragma unroll
  for (int w = 1; w < 16; ++w) fm = fmaxf(fm, red[w]);
#pragma unroll
  for (int k = 0; k < 8; ++k) {
    int i = t + k * 1024;
    float s = f1[i] + fm;
    mhat[i] = fmaxf(fmaxf(s, ALPHAV * s), MASKF);
  }
}

// ---------------- K3: FUSED adj + P-regen + (P@h) via 32x32x16 MFMA -------
// Wave = 32 rows x FULL 256 cols (acc 8 x f32x16): P computed ONCE chip-wide.
// Block = 4 waves (128 rows). grid (64, 8). 3 LDS bufs (16 KB ea), depth-2
// prefetch, counted vmcnt(8) = {4 adj int4 + 4 stage} per step, ONE barrier
// per 32-j step. X/Y/Z named adj register rotation. No setprio.
__global__ __launch_bounds__(256, 2) void k_spmm(
    const unsigned short* __restrict__ hTt,
    const int* __restrict__ adj,
    const float* __restrict__ f1, const float* __restrict__ f2,
    const float* __restrict__ mhat,
    float* __restrict__ part, float* __restrict__ rowsumP)
{
  __shared__ __align__(16) unsigned short hbuf[3 * 8192]; // 3 x 16 KB
  __shared__ __align__(16) float f2s[1024];               // pre-scaled by L2E
  const int t  = threadIdx.x;
  const int wv = t >> 6;
  const int l  = t & 63;
  const int lh = l >> 5;           // k-half of lane
  const int lm = l & 31;           // row (A) / col (B) within 32
  const int bx = blockIdx.x;
  const int ks = blockIdx.y;
  const int r0 = bx * 128;
  const int lh8 = lh * 8;

  const int rA = r0 + wv * 32 + lm;
  const float nmA   = -mhat[rA] * L2E;
  const float base0 = fmaf(f1[rA], L2E, nmA);
  const float c20   = nmA * (1.f - ALPHAV);
  const float mc0   = fmaf(MASKF, L2E, nmA);
  const int* aP = adj + (size_t)rA * NN + ks * 1024 + lh8;

  // f2 slice -> LDS (pre-scaled). Done before the counted stream starts.
  {
    float4 v = *(const float4*)(f2 + ks * 1024 + t * 4);
    v.x *= L2E; v.y *= L2E; v.z *= L2E; v.w *= L2E;
    *(float4*)(&f2s[t * 4]) = v;
  }
  __builtin_amdgcn_sched_barrier(0);

  f32x16 acc[8];
#pragma unroll
  for (int c = 0; c < 8; ++c)
#pragma unroll
    for (int e = 0; e < 16; ++e) acc[c][e] = 0.f;
  float sumP = 0.f;

  const unsigned short* gt0 = hTt + (size_t)ks * 32 * 8192;
  const char* cbase = (const char*)hbuf;

#define SB0 __builtin_amdgcn_sched_barrier(0)
#define STAGE(BUFI, JT)                                                       \
  do {                                                                        \
    const unsigned short* gp_ = gt0 + (size_t)(JT) * 8192 + t * 8;            \
    char* lp_ = ((char*)hbuf) + (BUFI) * 16384 + t * 16;                      \
    _Pragma("unroll")                                                         \
    for (int c = 0; c < 4; ++c) {                                             \
      __builtin_amdgcn_global_load_lds(                                       \
          (const __attribute__((address_space(1))) unsigned int*)(gp_ + c * 2048), \
          (__attribute__((address_space(3))) unsigned int*)(lp_ + c * 4096),  \
          16, 0, 0);                                                          \
    }                                                                         \
  } while (0)

#define ADJ(S0, S1, S2, S3, JT)                                               \
  do {                                                                        \
    S0 = *(const int4*)(aP + (JT) * 32);                                      \
    S1 = *(const int4*)(aP + (JT) * 32 + 4);                                  \
    S2 = *(const int4*)(aP + (JT) * 32 + 16);                                 \
    S3 = *(const int4*)(aP + (JT) * 32 + 20);                                 \
  } while (0)

#define REGEN8(AFR, A0, A1, FB)                                               \
  do {                                                                        \
    float4 fx_ = *(const float4*)(&f2s[FB]);                                  \
    float4 fy_ = *(const float4*)(&f2s[(FB) + 4]);                            \
    float fv_[8] = {fx_.x, fx_.y, fx_.z, fx_.w, fy_.x, fy_.y, fy_.z, fy_.w};  \
    int av_[8] = {A0.x, A0.y, A0.z, A0.w, A1.x, A1.y, A1.z, A1.w};            \
    _Pragma("unroll")                                                         \
    for (int b = 0; b < 8; ++b) {                                             \
      float u_ = base0 + fv_[b];                                              \
      float w_ = fmaxf(u_, fmaf(ALPHAV, u_, c20));                            \
      w_ = (av_[b] > 0) ? w_ : mc0;                                           \
      float p_ = ex2(w_);                                                     \
      sumP += p_;                                                             \
      AFR[b] = (short)f2bf(p_);                                               \
    }                                                                         \
  } while (0)

// One 32-j step: wait own counted stream, barrier, issue step+2, regen P,
// then 16 ds_read + 16 MFMA. BUF/NBUF are compile-time literals.
#define TS(JT, BUF, NBUF, C0, C1, C2, C3, I0, I1, I2, I3, DOISSUE, VMC)       \
  do {                                                                        \
    asm volatile("s_waitcnt vmcnt(" #VMC ")" ::: "memory");                   \
    __builtin_amdgcn_s_barrier();                                             \
    SB0;                                                                      \
    if (DOISSUE) {                                                            \
      ADJ(I0, I1, I2, I3, (JT) + 2);                                          \
      STAGE(NBUF, (JT) + 2);                                                  \
    }                                                                         \
    SB0;                                                                      \
    bf16x8 afr0_, afr1_;                                                      \
    REGEN8(afr0_, C0, C1, (JT) * 32 + lh8);                                   \
    REGEN8(afr1_, C2, C3, (JT) * 32 + 16 + lh8);                              \
    SB0;                                                                      \
    const char* lb_ = cbase + (BUF) * 16384;                                  \
    const int g0_ = lh * 4096;                                                \
    const int g1_ = (2 + lh) * 4096;                                          \
    const int cb_ = lm * 16;                                                  \
    _Pragma("unroll")                                                         \
    for (int c = 0; c < 8; ++c) {                                             \
      bf16x8 b0_ = *(const bf16x8*)(lb_ + g0_ + c * 512 + cb_);               \
      acc[c] = __builtin_amdgcn_mfma_f32_32x32x16_bf16(afr0_, b0_, acc[c], 0, 0, 0); \
      bf16x8 b1_ = *(const bf16x8*)(lb_ + g1_ + c * 512 + cb_);               \
      acc[c] = __builtin_amdgcn_mfma_f32_32x32x16_bf16(afr1_, b1_, acc[c], 0, 0, 0); \
    }                                                                         \
  } while (0)

  int4 X0, X1, X2, X3, Y0, Y1, Y2, Y3, Z0, Z1, Z2, Z3;

  // prologue: counted stream = [adjX(0) x4, stage(0) x4, adjY(1) x4, stage(1) x4]
  ADJ(X0, X1, X2, X3, 0);
  STAGE(0, 0);
  SB0;
  ADJ(Y0, Y1, Y2, Y3, 1);
  STAGE(1, 1);
  asm volatile("s_waitcnt lgkmcnt(0)" ::: "memory");  // f2s visible
  __builtin_amdgcn_s_barrier();
  SB0;

#pragma unroll 1
  for (int p = 0; p < 10; ++p) {
    const int s0 = p * 3;
    TS(s0 + 0, 0, 2, X0, X1, X2, X3, Z0, Z1, Z2, Z3, 1, 8);
    TS(s0 + 1, 1, 0, Y0, Y1, Y2, Y3, X0, X1, X2, X3, 1, 8);
    TS(s0 + 2, 2, 1, Z0, Z1, Z2, Z3, Y0, Y1, Y2, Y3, 1, 8);
  }
  TS(30, 0, 2, X0, X1, X2, X3, Z0, Z1, Z2, Z3, 0, 8);
  TS(31, 1, 0, Y0, Y1, Y2, Y3, X0, X1, X2, X3, 0, 0);

#undef SB0
#undef STAGE
#undef ADJ
#undef REGEN8
#undef TS

  // rowsum: lanes l and l^32 hold the two k-halves of row lm
  sumP += __shfl_xor(sumP, 32);
  if (lh == 0) rowsumP[(size_t)ks * NN + rA] = sumP;

  // C-write: col = c*32 + lm; row = r0 + wv*32 + 4*lh + (reg&3) + 8*(reg>>2)
  float* dst = part + (size_t)ks * NN * FOUT;
  const int rowb = r0 + wv * 32 + 4 * lh;
#pragma unroll
  for (int c = 0; c < 8; ++c) {
    const int col = c * 32 + lm;
#pragma unroll
    for (int reg = 0; reg < 16; ++reg) {
      int row = rowb + (reg & 3) + 8 * (reg >> 2);
      dst[(size_t)row * FOUT + col] = acc[c][reg];
    }
  }
}

// ---------------- K4: sum 8 K-partials + rowsums, normalize ---------------
__global__ __launch_bounds__(256) void k_fin(
    float* __restrict__ outp, const float* __restrict__ part,
    const float* __restrict__ rowsumP)
{
  const int idx4 = blockIdx.x * 256 + threadIdx.x;
  const size_t e = (size_t)idx4 * 4;
  const int i = (int)(e >> 8);
  float rs = 0.f;
#pragma unroll
  for (int p = 0; p < 8; ++p) rs += rowsumP[(size_t)p * NN + i];
  float4 o = {0.f, 0.f, 0.f, 0.f};
#pragma unroll
  for (int p = 0; p < 8; ++p) {
    float4 pv = *(const float4*)(part + (size_t)p * NN * FOUT + e);
    o.x += pv.x; o.y += pv.y; o.z += pv.z; o.w += pv.w;
  }
  float inv = 1.f / rs;
  o.x *= inv; o.y *= inv; o.z *= inv; o.w *= inv;
  *(float4*)(outp + e) = o;
}

extern "C" void kernel_launch(void* const* d_in, const int* in_sizes, int n_in,
                              void* d_out, int out_size, void* d_ws, size_t ws_size,
                              hipStream_t stream)
{
  const float* x  = (const float*)d_in[0];
  const int* adj  = (const int*)d_in[1];
  const float* Wm = (const float*)d_in[2];
  const float* aG = (const float*)d_in[3];
  float* outp = (float*)d_out;

  char* w = (char*)d_ws;
  unsigned short* hTt = (unsigned short*)(w + 0);            // 4 MB (tiled)
  float* f1           = (float*)(w + 4194304);               // 32 KB
  float* f2           = (float*)(w + 4227072);               // 32 KB
  float* mhat         = (float*)(w + 4259840);               // 32 KB
  float* rowsumP      = (float*)(w + 4292608);               // 256 KB
  float* part         = (float*)(w + 4554752);               // 64 MB (8 slices)

  hipLaunchKernelGGL(k_gemm_h, dim3(512),   dim3(256),  0, stream, x, Wm, aG, hTt, f1, f2);
  hipLaunchKernelGGL(k_bound,  dim3(1),     dim3(1024), 0, stream, f1, f2, mhat);
  hipLaunchKernelGGL(k_spmm,   dim3(64, 8), dim3(256),  0, stream, hTt, adj, f1, f2, mhat, part, rowsumP);
  hipLaunchKernelGGL(k_fin,    dim3(2048),  dim3(256),  0, stream, outp, part, rowsumP);
}